// Round 9
// baseline (531.682 us; speedup 1.0000x reference)
//
#include <hip/hip_runtime.h>

typedef unsigned short ushort_t;
typedef __attribute__((ext_vector_type(8))) short short8;
typedef __attribute__((ext_vector_type(4))) float f32x4;

#define DEV __device__ __forceinline__

DEV float sigm(float x) { return 1.0f / (1.0f + __expf(-x)); }
DEV float tanh_fast(float x) { return 1.0f - 2.0f / (__expf(2.0f * x) + 1.0f); }
DEV ushort_t f2bf(float v) {
    unsigned u = __float_as_uint(v);
    unsigned r = (u + 0x7fffu + ((u >> 16) & 1u)) >> 16;
    return (ushort_t)r;
}
DEV float bf2f(ushort_t h) { return __uint_as_float(((unsigned)h) << 16); }
DEV unsigned cvt_pk(float lo, float hi) {
    unsigned r;
    asm("v_cvt_pk_bf16_f32 %0, %1, %2" : "=v"(r) : "v"(lo), "v"(hi));
    return r;
}
DEV float dot4(float4 a, float4 b) {
    return fmaf(a.x, b.x, fmaf(a.y, b.y, fmaf(a.z, b.z, a.w * b.w)));
}

// ---------------------------------------------------------------------------
// Fused preprocess kernel: block roles by blockIdx.x.
//  [0, nodeB)              : node precompute (MFMA)
//  [nodeB, nodeB+tableB)   : per-rel / per-query tables
//  [nodeB+tableB, ...)     : obj histogram
// Tables (R5 layout, all gather rows cache-dense):
//  gate_hs[n][256] bf16 packed (u_d, r_d) ; ws_hs[n][64] bf16 ; hsb[n][128] bf16
//  grhr[r][256] f32 packed ; whr[r][64] ; thr[r][128] ; gq[q][256] ; wq[q][64]
// ---------------------------------------------------------------------------
__global__ __launch_bounds__(256) void prep_kernel(
    const float* __restrict__ hidden, const float* __restrict__ gateW,
    const float* __restrict__ WsW,
    ushort_t* __restrict__ gate_hs, ushort_t* __restrict__ ws_hs,
    ushort_t* __restrict__ hsb, int nNode,
    const float* __restrict__ rela, const int* __restrict__ q_rel,
    const float* __restrict__ gateW_b,
    const float* __restrict__ WrW, const float* __restrict__ WqrW,
    const float* __restrict__ Wqr_b, const float* __restrict__ htW,
    const float* __restrict__ ht_b,
    float* __restrict__ grhr, float* __restrict__ gq,
    float* __restrict__ whr, float* __restrict__ wq,
    float* __restrict__ thr, int vocab,
    const int* __restrict__ edges, int nEdge, int* __restrict__ cnt,
    int nodeB, int tableB)
{
    __shared__ char smem[8192];
    int bid = blockIdx.x, t = threadIdx.x;

    if (bid < nodeB) {
        // ---------------- node path ----------------
        char* a_lds = smem;
        int w = t >> 6, l = t & 63;
        int lm = l & 15, lh = l >> 4;
        int nbase = bid * 32;

        for (int idx = t; idx < 1024; idx += 256) {
            int row = idx >> 5, c4 = idx & 31;
            int node = nbase + row;
            float4 v = (node < nNode) ? ((const float4*)hidden)[(size_t)node * 32 + c4]
                                      : float4{0.f, 0.f, 0.f, 0.f};
            uint2 p;
            p.x = cvt_pk(v.x, v.y);
            p.y = cvt_pk(v.z, v.w);
            *(uint2*)(a_lds + ((row * 256 + c4 * 8) ^ ((row & 7) << 4))) = p;
            if (node < nNode) *(uint2*)(hsb + (size_t)node * 128 + c4 * 4) = p;
        }

        short8 bfr[5][4];
#pragma unroll
        for (int nt = 0; nt < 5; nt++)
#pragma unroll
            for (int kt = 0; kt < 4; kt++) {
                int row = w * 80 + nt * 16 + lm;
                const float* src = (row < 256)
                    ? gateW + (size_t)row * 384 + 256 + kt * 32 + lh * 8
                    : WsW + (size_t)(row - 256) * 128 + kt * 32 + lh * 8;
                float4 f0 = *(const float4*)src;
                float4 f1 = *(const float4*)(src + 4);
                union { unsigned u[4]; short8 s; } tmp;
                tmp.u[0] = cvt_pk(f0.x, f0.y); tmp.u[1] = cvt_pk(f0.z, f0.w);
                tmp.u[2] = cvt_pk(f1.x, f1.y); tmp.u[3] = cvt_pk(f1.z, f1.w);
                bfr[nt][kt] = tmp.s;
            }
        __syncthreads();

        short8 afr[2][4];
#pragma unroll
        for (int mt = 0; mt < 2; mt++)
#pragma unroll
            for (int kt = 0; kt < 4; kt++) {
                int row = mt * 16 + lm;
                afr[mt][kt] = *(const short8*)(a_lds +
                    ((row * 256 + kt * 64 + lh * 16) ^ ((row & 7) << 4)));
            }
        f32x4 acc[2][5];
#pragma unroll
        for (int mt = 0; mt < 2; mt++)
#pragma unroll
            for (int nt = 0; nt < 5; nt++) acc[mt][nt] = (f32x4){0.f, 0.f, 0.f, 0.f};
#pragma unroll
        for (int kt = 0; kt < 4; kt++)
#pragma unroll
            for (int mt = 0; mt < 2; mt++)
#pragma unroll
                for (int nt = 0; nt < 5; nt++)
                    acc[mt][nt] = __builtin_amdgcn_mfma_f32_16x16x32_bf16(
                        afr[mt][kt], bfr[nt][kt], acc[mt][nt], 0, 0, 0);

#pragma unroll
        for (int mt = 0; mt < 2; mt++)
#pragma unroll
            for (int nt = 0; nt < 5; nt++) {
                int wrow = w * 80 + nt * 16 + lm;
#pragma unroll
                for (int r = 0; r < 4; r++) {
                    int node = nbase + mt * 16 + lh * 4 + r;
                    if (node < nNode) {
                        ushort_t v = f2bf(acc[mt][nt][r]);
                        if (wrow < 256)
                            gate_hs[(size_t)node * 256 + 2 * (wrow & 127) + (wrow >> 7)] = v;
                        else
                            ws_hs[(size_t)node * 64 + wrow - 256] = v;
                    }
                }
            }
    } else if (bid < nodeB + tableB) {
        // ---------------- table path ----------------
        float* x = (float*)smem;
        int b = bid - nodeB;
        bool isRel = b < vocab;
        int src = isRel ? b : q_rel[b - vocab];
        if (t < 128) x[t] = rela[src * 128 + t];
        __syncthreads();
        const float4* x4 = (const float4*)x;
        {
            const float4* wrow = (const float4*)(gateW + t * 384 + (isRel ? 0 : 128));
            float acc = isRel ? 0.0f : gateW_b[t];
#pragma unroll 8
            for (int i = 0; i < 32; i++) acc += dot4(wrow[i], x4[i]);
            float* dst = isRel ? (grhr + b * 256) : (gq + (b - vocab) * 256);
            dst[2 * (t & 127) + (t >> 7)] = acc;
        }
        if (isRel) {
            if (t < 192) {
                bool isWr = t < 64;
                int i = isWr ? t : (t - 64);
                const float* wp = isWr ? (WrW + i * 128) : (htW + i * 256);
                const float4* wrow = (const float4*)wp;
                float acc = isWr ? 0.0f : ht_b[i];
#pragma unroll 8
                for (int q = 0; q < 32; q++) acc += dot4(wrow[q], x4[q]);
                if (isWr) whr[b * 64 + i] = acc;
                else      thr[b * 128 + i] = acc;
            }
        } else {
            if (t < 64) {
                const float4* wrow = (const float4*)(WqrW + t * 128);
                float acc = Wqr_b[t];
#pragma unroll 8
                for (int q = 0; q < 32; q++) acc += dot4(wrow[q], x4[q]);
                wq[(b - vocab) * 64 + t] = acc;
            }
        }
    } else {
        // ---------------- hist path ----------------
        int i = (bid - nodeB - tableB) * 256 + t;
        if (i < nEdge) atomicAdd(cnt + edges[(size_t)i * 7 + 5], 1);
    }
}

// ---------------------------------------------------------------------------
// Scan (two-level, R5-proven) over obj counts.
// ---------------------------------------------------------------------------
__global__ __launch_bounds__(256) void scan1_kernel(
    const int* __restrict__ cnt, int n, int* __restrict__ partials)
{
    __shared__ int s[256];
    int t = threadIdx.x;
    int i = blockIdx.x * 256 + t;
    s[t] = (i < n) ? cnt[i] : 0;
    __syncthreads();
    for (int o = 128; o > 0; o >>= 1) {
        if (t < o) s[t] += s[t + o];
        __syncthreads();
    }
    if (t == 0) partials[blockIdx.x] = s[0];
}

__global__ __launch_bounds__(256) void scan2_kernel(
    const int* __restrict__ cnt, int n, const int* __restrict__ partials,
    int nBlk, int* __restrict__ cursor)
{
    __shared__ int ps[256];
    __shared__ int loc[256];
    int t = threadIdx.x, b = blockIdx.x;
    ps[t] = (t < nBlk) ? partials[t] : 0;
    __syncthreads();
    for (int o = 1; o < 256; o <<= 1) {
        int v = (t >= o) ? ps[t - o] : 0;
        __syncthreads();
        ps[t] += v;
        __syncthreads();
    }
    int offset = (b > 0) ? ps[b - 1] : 0;
    int i = b * 256 + t;
    int v = (i < n) ? cnt[i] : 0;
    loc[t] = v;
    __syncthreads();
    for (int o = 1; o < 256; o <<= 1) {
        int x = (t >= o) ? loc[t - o] : 0;
        __syncthreads();
        loc[t] += x;
        __syncthreads();
    }
    if (i < n) cursor[i] = offset + loc[t] - v;
}

// ---------------------------------------------------------------------------
// Build: 8-byte packed sorted entries. x = sub | ridx<<16 | rel<<22 ; y = obj.
// (sub < 65536, ridx < 64, rel < 512 — all hold for this problem.)
// ---------------------------------------------------------------------------
__global__ __launch_bounds__(256) void build_kernel(
    const int* __restrict__ edges, int nEdge, int* __restrict__ cursor,
    uint2* __restrict__ sorted)
{
    int i = blockIdx.x * 256 + threadIdx.x;
    if (i < nEdge) {
        const int* er = edges + (size_t)i * 7;
        int obj = er[5];
        int s = atomicAdd(cursor + obj, 1);
        uint2 p;
        p.x = (unsigned)er[4] | ((unsigned)er[0] << 16) | ((unsigned)er[2] << 22);
        p.y = (unsigned)obj;
        sorted[s] = p;
    }
}

// ---------------------------------------------------------------------------
// Edge kernel (R5 structure + K contiguous batches/block): 4 waves; wave w owns
// dims [32w,32w+32); 32 obj-sorted edges per batch. LDS ~26 KB -> 6 blocks/CU.
// Per batch: loop A (independent per-edge gather+gates, x->xb, (A',B')->ab,
// aa partial), acc=thr preload, batched butterflies, eds4 prefetch, MFMA
// (C preloaded), run-reduced atomics. B-fragments loaded once per block.
// ---------------------------------------------------------------------------
__global__ __launch_bounds__(256, 6) void edge_kernel(
    const uint2* __restrict__ sorted, int nEdge, int nBatch, int K,
    const float* __restrict__ grhr, const float* __restrict__ gq,
    const float* __restrict__ whr, const float* __restrict__ wq,
    const float* __restrict__ thr,
    const ushort_t* __restrict__ gate_hs, const ushort_t* __restrict__ ws_hs,
    const ushort_t* __restrict__ hsb,
    const float* __restrict__ walpha, const float* __restrict__ htW,
    float* __restrict__ agg)
{
    __shared__ ushort_t xb[32 * 128];   // 8 KB, x bf16, swz ^((e&7)<<4)
    __shared__ unsigned ab[32 * 128];   // 16 KB, (A',B') bf16 pair, swz ^(((e>>2)&3)<<6)
    __shared__ float sgaL[32];
    __shared__ int4 eds4[2][32];

    int t = threadIdx.x, w = t >> 6, l = t & 63;
    int lm = l & 15, lh = l >> 4;
    int n0 = w * 32;

    // bijective XCD swizzle over chunks: contiguous batch (= obj) ranges per XCD
    int nb = gridDim.x;
    int xcd = blockIdx.x & 7, lid = blockIdx.x >> 3;
    int q = nb >> 3, rr = nb & 7;
    int chunk = ((xcd < rr) ? xcd * (q + 1) : rr * (q + 1) + (xcd - rr) * q) + lid;
    int b0 = chunk * K;
    int b1 = min(b0 + K, nBatch);
    if (b0 >= nBatch) return;

    if (t < 32) {
        int gi = b0 * 32 + t;
        if (gi < nEdge) {
            uint2 p = sorted[gi];
            eds4[0][t] = make_int4((int)((p.x >> 16) & 63u), (int)(p.x >> 22),
                                   (int)(p.x & 0xffffu), (int)p.y);
        } else {
            eds4[0][t] = make_int4(0, 0, 0, -1);
        }
    }

    // B fragments (W2 = htW[:,128:256] bf16) in VGPRs, once per block
    short8 bfr[2][4];
#pragma unroll
    for (int nt = 0; nt < 2; nt++)
#pragma unroll
        for (int kt = 0; kt < 4; kt++) {
            const float* src = htW + (size_t)(n0 + nt * 16 + lm) * 256 + 128 + kt * 32 + lh * 8;
            float4 f0 = *(const float4*)src;
            float4 f1 = *(const float4*)(src + 4);
            union { unsigned u[4]; short8 s; } tmp;
            tmp.u[0] = cvt_pk(f0.x, f0.y); tmp.u[1] = cvt_pk(f0.z, f0.w);
            tmp.u[2] = cvt_pk(f1.x, f1.y); tmp.u[3] = cvt_pk(f1.z, f1.w);
            bfr[nt][kt] = tmp.s;
        }
    float wal = walpha[l];
    __syncthreads();   // eds4[0] ready

    int cur = 0;
    for (int b = b0; b < b1; ++b) {
        // --- Loop A: independent per-edge work (8 edges per wave) ---
        float aa8[8];
#pragma unroll
        for (int i = 0; i < 8; i++) {
            int e = w * 8 + i;
            int4 er = eds4[cur][e];
            int ridx = er.x, rel = er.y, sub = er.z;
            ushort4 gp = *(const ushort4*)(gate_hs + (size_t)sub * 256 + 4 * l);
            float4 ga = *(const float4*)(grhr + (size_t)rel * 256 + 4 * l);
            float4 gb = *(const float4*)(gq + (size_t)ridx * 256 + 4 * l);
            unsigned hp = *(const unsigned*)(hsb + (size_t)sub * 128 + 2 * l);
            float aw = bf2f(ws_hs[(size_t)sub * 64 + l]) + whr[rel * 64 + l] + wq[ridx * 64 + l];
            float h0 = bf2f((ushort_t)(hp & 0xffffu));
            float h1 = bf2f((ushort_t)(hp >> 16));
            float u0 = sigm(ga.x + gb.x + bf2f(gp.x));
            float r0 = sigm(ga.y + gb.y + bf2f(gp.y));
            float u1 = sigm(ga.z + gb.z + bf2f(gp.z));
            float r1 = sigm(ga.w + gb.w + bf2f(gp.w));
            *(unsigned*)((char*)xb + ((e * 256 + 4 * l) ^ ((e & 7) << 4))) = cvt_pk(r0 * h0, r1 * h1);
            uint2 abp;
            abp.x = cvt_pk((1.0f - u0) * h0, u0);
            abp.y = cvt_pk((1.0f - u1) * h1, u1);
            *(uint2*)((char*)ab + ((e * 512 + 8 * l) ^ (((e >> 2) & 3) << 6))) = abp;
            aa8[i] = fmaxf(aw, 0.01f * aw) * wal;
        }

        // --- acc init = thr[rel][d] (C of MFMA); latency hidden under butterflies ---
        f32x4 acc[2][2];
#pragma unroll
        for (int mt = 0; mt < 2; mt++)
#pragma unroll
            for (int nt = 0; nt < 2; nt++) {
                int d = n0 + nt * 16 + lm;
#pragma unroll
                for (int r = 0; r < 4; r++) {
                    int rel = eds4[cur][mt * 16 + lh * 4 + r].y;
                    acc[mt][nt][r] = thr[rel * 128 + d];
                }
            }

        // --- batched butterflies (8-way ILP) ---
#pragma unroll
        for (int o = 32; o > 0; o >>= 1) {
#pragma unroll
            for (int i = 0; i < 8; i++) aa8[i] += __shfl_xor(aa8[i], o, 64);
        }
#pragma unroll
        for (int i = 0; i < 8; i++) {
            float s = sigm(aa8[i]);
            if (l == i) sgaL[w * 8 + i] = s;
        }

        // prefetch next batch's packed edge records
        if (b + 1 < b1 && t < 32) {
            int gi = (b + 1) * 32 + t;
            if (gi < nEdge) {
                uint2 p = sorted[gi];
                eds4[cur ^ 1][t] = make_int4((int)((p.x >> 16) & 63u), (int)(p.x >> 22),
                                             (int)(p.x & 0xffffu), (int)p.y);
            } else {
                eds4[cur ^ 1][t] = make_int4(0, 0, 0, -1);
            }
        }
        __syncthreads();   // xb/ab/sgaL ready; eds4[nxt] staged

        // --- Phase 2: MFMA C[32 edges][32 dims] (C pre-loaded with thr) ---
        short8 afr[2][4];
#pragma unroll
        for (int mt = 0; mt < 2; mt++)
#pragma unroll
            for (int kt = 0; kt < 4; kt++) {
                int e = mt * 16 + lm;
                afr[mt][kt] = *(const short8*)((const char*)xb +
                    ((e * 256 + kt * 64 + lh * 16) ^ ((e & 7) << 4)));
            }
#pragma unroll
        for (int kt = 0; kt < 4; kt++)
#pragma unroll
            for (int mt = 0; mt < 2; mt++)
#pragma unroll
                for (int nt = 0; nt < 2; nt++)
                    acc[mt][nt] = __builtin_amdgcn_mfma_f32_16x16x32_bf16(
                        afr[mt][kt], bfr[nt][kt], acc[mt][nt], 0, 0, 0);

        // --- Epilogue: run-reduced atomics along each lane's 4 consecutive edges ---
#pragma unroll
        for (int mt = 0; mt < 2; mt++)
#pragma unroll
            for (int nt = 0; nt < 2; nt++) {
                int d = n0 + nt * 16 + lm;
                float vals[4];
                int objs[4];
#pragma unroll
                for (int r = 0; r < 4; r++) {
                    int e = mt * 16 + lh * 4 + r;
                    objs[r] = eds4[cur][e].w;
                    float cand = tanh_fast(acc[mt][nt][r]);
                    unsigned abw = *(const unsigned*)((const char*)ab +
                        ((e * 512 + 4 * d) ^ (((e >> 2) & 3) << 6)));
                    vals[r] = sgaL[e] * (bf2f((ushort_t)(abw & 0xffffu)) +
                                         bf2f((ushort_t)(abw >> 16)) * cand);
                }
                float sum = vals[0];
                int prev = objs[0];
#pragma unroll
                for (int r = 1; r < 4; r++) {
                    if (objs[r] == prev) {
                        sum += vals[r];
                    } else {
                        if (prev >= 0) atomicAdd(agg + (size_t)prev * 128 + d, sum);
                        sum = vals[r];
                        prev = objs[r];
                    }
                }
                if (prev >= 0) atomicAdd(agg + (size_t)prev * 128 + d, sum);
            }
        __syncthreads();   // all reads of xb/ab/sgaL/eds4[cur] done
        cur ^= 1;
    }
}

// ---------------------------------------------------------------------------
// Final (MFMA): out[n] = (agg[n]/sqrt(deg[n]+1e-4)) @ Wh.T, in place.
// ---------------------------------------------------------------------------
__global__ __launch_bounds__(256) void final_kernel(
    const float* __restrict__ WhW, const int* __restrict__ degi,
    float* __restrict__ agg, int nNode)
{
    __shared__ char y_lds[64 * 256];
    int t = threadIdx.x, w = t >> 6, l = t & 63;
    int lm = l & 15, lh = l >> 4;
    int nbase = blockIdx.x * 64;

    short8 bfr[2][4];
#pragma unroll
    for (int nt = 0; nt < 2; nt++)
#pragma unroll
        for (int kt = 0; kt < 4; kt++) {
            const float* src = WhW + (size_t)(w * 32 + nt * 16 + lm) * 128 + kt * 32 + lh * 8;
            float4 f0 = *(const float4*)src;
            float4 f1 = *(const float4*)(src + 4);
            union { unsigned u[4]; short8 s; } tmp;
            tmp.u[0] = cvt_pk(f0.x, f0.y); tmp.u[1] = cvt_pk(f0.z, f0.w);
            tmp.u[2] = cvt_pk(f1.x, f1.y); tmp.u[3] = cvt_pk(f1.z, f1.w);
            bfr[nt][kt] = tmp.s;
        }

    for (int idx = t; idx < 2048; idx += 256) {
        int row = idx >> 5, c4 = idx & 31;
        int node = nbase + row;
        uint2 p = {0u, 0u};
        if (node < nNode) {
            float4 v = ((const float4*)agg)[(size_t)node * 32 + c4];
            float r = 1.0f / sqrtf((float)degi[node] + 1e-4f);
            p.x = cvt_pk(v.x * r, v.y * r);
            p.y = cvt_pk(v.z * r, v.w * r);
        }
        *(uint2*)(y_lds + ((row * 256 + c4 * 8) ^ ((row & 7) << 4))) = p;
    }
    __syncthreads();

    short8 afr[4][4];
#pragma unroll
    for (int mt = 0; mt < 4; mt++)
#pragma unroll
        for (int kt = 0; kt < 4; kt++) {
            int row = mt * 16 + lm;
            afr[mt][kt] = *(const short8*)(y_lds +
                ((row * 256 + kt * 64 + lh * 16) ^ ((row & 7) << 4)));
        }
    f32x4 acc[4][2];
#pragma unroll
    for (int mt = 0; mt < 4; mt++)
#pragma unroll
        for (int nt = 0; nt < 2; nt++) acc[mt][nt] = (f32x4){0.f, 0.f, 0.f, 0.f};
#pragma unroll
    for (int kt = 0; kt < 4; kt++)
#pragma unroll
        for (int mt = 0; mt < 4; mt++)
#pragma unroll
            for (int nt = 0; nt < 2; nt++)
                acc[mt][nt] = __builtin_amdgcn_mfma_f32_16x16x32_bf16(
                    afr[mt][kt], bfr[nt][kt], acc[mt][nt], 0, 0, 0);

#pragma unroll
    for (int mt = 0; mt < 4; mt++)
#pragma unroll
        for (int nt = 0; nt < 2; nt++) {
            int col = w * 32 + nt * 16 + lm;
#pragma unroll
            for (int r = 0; r < 4; r++) {
                int node = nbase + mt * 16 + lh * 4 + r;
                if (node < nNode) agg[(size_t)node * 128 + col] = acc[mt][nt][r];
            }
        }
}

extern "C" void kernel_launch(void* const* d_in, const int* in_sizes, int n_in,
                              void* d_out, int out_size, void* d_ws, size_t ws_size,
                              hipStream_t stream)
{
    const int*   q_rel   = (const int*)d_in[1];
    const float* hidden  = (const float*)d_in[2];
    const int*   edges   = (const int*)d_in[3];
    const float* rela    = (const float*)d_in[5];
    const float* WsW     = (const float*)d_in[6];
    const float* WrW     = (const float*)d_in[7];
    const float* WqrW    = (const float*)d_in[8];
    const float* Wqr_b   = (const float*)d_in[9];
    const float* walpha  = (const float*)d_in[10];
    const float* gateW   = (const float*)d_in[11];
    const float* gateW_b = (const float*)d_in[12];
    const float* htW     = (const float*)d_in[13];
    const float* ht_b    = (const float*)d_in[14];
    const float* WhW     = (const float*)d_in[15];

    int nNode  = in_sizes[2] / 128;
    int nEdge  = in_sizes[3] / 7;
    int vocab  = in_sizes[5] / 128;
    int nQuery = in_sizes[1];

    char* ws = (char*)d_ws;
    size_t off = 0;
    auto alloc = [&](size_t bytes) { size_t o = off; off += (bytes + 255) & ~(size_t)255; return o; };
    int*      cntO    = (int*)(ws + alloc((size_t)(nNode + 256) * 4));
    int*      cursorO = (int*)(ws + alloc((size_t)(nNode + 256) * 4));
    int*      partials= (int*)(ws + alloc(256 * 4));
    uint2*    sorted  = (uint2*)(ws + alloc((size_t)nEdge * 8));
    float*    grhr    = (float*)(ws + alloc((size_t)vocab * 256 * 4));
    float*    whr     = (float*)(ws + alloc((size_t)vocab * 64 * 4));
    float*    thr     = (float*)(ws + alloc((size_t)vocab * 128 * 4));
    float*    gq      = (float*)(ws + alloc((size_t)nQuery * 256 * 4));
    float*    wq      = (float*)(ws + alloc((size_t)nQuery * 64 * 4));
    ushort_t* gate_hs = (ushort_t*)(ws + alloc((size_t)nNode * 256 * 2));
    ushort_t* ws_hs   = (ushort_t*)(ws + alloc((size_t)nNode * 64 * 2));
    ushort_t* hsb     = (ushort_t*)(ws + alloc((size_t)nNode * 128 * 2));
    if (off > ws_size) return;

    float* agg = (float*)d_out;
    hipMemsetAsync(agg, 0, (size_t)nNode * 128 * 4, stream);
    hipMemsetAsync(cntO, 0, (size_t)(nNode + 256) * 4, stream);

    int nodeB  = (nNode + 31) / 32;
    int tableB = vocab + nQuery;
    int histB  = (nEdge + 255) / 256;
    prep_kernel<<<nodeB + tableB + histB, 256, 0, stream>>>(
        hidden, gateW, WsW, gate_hs, ws_hs, hsb, nNode,
        rela, q_rel, gateW_b, WrW, WqrW, Wqr_b, htW, ht_b,
        grhr, gq, whr, wq, thr, vocab,
        edges, nEdge, cntO, nodeB, tableB);

    int nScan = nNode + 1;
    int nBlk = (nScan + 255) / 256;
    scan1_kernel<<<nBlk, 256, 0, stream>>>(cntO, nScan, partials);
    scan2_kernel<<<nBlk, 256, 0, stream>>>(cntO, nScan, partials, nBlk, cursorO);
    build_kernel<<<(nEdge + 255) / 256, 256, 0, stream>>>(edges, nEdge, cursorO, sorted);

    int nBatch = (nEdge + 31) / 32;
    int K = 4;
    int nChunks = (nBatch + K - 1) / K;
    edge_kernel<<<nChunks, 256, 0, stream>>>(
        sorted, nEdge, nBatch, K, grhr, gq, whr, wq, thr,
        gate_hs, ws_hs, hsb, walpha, htW, agg);

    int fblocks = (nNode + 63) / 64;
    final_kernel<<<fblocks, 256, 0, stream>>>(WhW, cntO, agg, nNode);
}

// Round 10
// 375.779 us; speedup vs baseline: 1.4149x; 1.4149x over previous
//
#include <hip/hip_runtime.h>

typedef unsigned short ushort_t;
typedef __attribute__((ext_vector_type(8))) short short8;
typedef __attribute__((ext_vector_type(4))) float f32x4;

#define DEV __device__ __forceinline__

DEV float sigm(float x) { return 1.0f / (1.0f + __expf(-x)); }
DEV float tanh_fast(float x) { return 1.0f - 2.0f / (__expf(2.0f * x) + 1.0f); }
DEV ushort_t f2bf(float v) {
    unsigned u = __float_as_uint(v);
    unsigned r = (u + 0x7fffu + ((u >> 16) & 1u)) >> 16;
    return (ushort_t)r;
}
DEV float bf2f(ushort_t h) { return __uint_as_float(((unsigned)h) << 16); }
DEV unsigned cvt_pk(float lo, float hi) {
    unsigned r;
    asm("v_cvt_pk_bf16_f32 %0, %1, %2" : "=v"(r) : "v"(lo), "v"(hi));
    return r;
}
DEV float dot4(float4 a, float4 b) {
    return fmaf(a.x, b.x, fmaf(a.y, b.y, fmaf(a.z, b.z, a.w * b.w)));
}

// ---------------------------------------------------------------------------
// Fused preprocess kernel: block roles by blockIdx.x.
//  [0, nodeB)              : node precompute (MFMA)
//  [nodeB, nodeB+tableB)   : per-rel / per-query tables
//  [nodeB+tableB, ...)     : obj histogram
// ---------------------------------------------------------------------------
__global__ __launch_bounds__(256) void prep_kernel(
    const float* __restrict__ hidden, const float* __restrict__ gateW,
    const float* __restrict__ WsW,
    ushort_t* __restrict__ gate_hs, ushort_t* __restrict__ ws_hs,
    ushort_t* __restrict__ hsb, int nNode,
    const float* __restrict__ rela, const int* __restrict__ q_rel,
    const float* __restrict__ gateW_b,
    const float* __restrict__ WrW, const float* __restrict__ WqrW,
    const float* __restrict__ Wqr_b, const float* __restrict__ htW,
    const float* __restrict__ ht_b,
    float* __restrict__ grhr, float* __restrict__ gq,
    float* __restrict__ whr, float* __restrict__ wq,
    float* __restrict__ thr, int vocab,
    const int* __restrict__ edges, int nEdge, int* __restrict__ cnt,
    int nodeB, int tableB)
{
    __shared__ char smem[8192];
    int bid = blockIdx.x, t = threadIdx.x;

    if (bid < nodeB) {
        // ---------------- node path ----------------
        char* a_lds = smem;
        int w = t >> 6, l = t & 63;
        int lm = l & 15, lh = l >> 4;
        int nbase = bid * 32;

        for (int idx = t; idx < 1024; idx += 256) {
            int row = idx >> 5, c4 = idx & 31;
            int node = nbase + row;
            float4 v = (node < nNode) ? ((const float4*)hidden)[(size_t)node * 32 + c4]
                                      : float4{0.f, 0.f, 0.f, 0.f};
            uint2 p;
            p.x = cvt_pk(v.x, v.y);
            p.y = cvt_pk(v.z, v.w);
            *(uint2*)(a_lds + ((row * 256 + c4 * 8) ^ ((row & 7) << 4))) = p;
            if (node < nNode) *(uint2*)(hsb + (size_t)node * 128 + c4 * 4) = p;
        }

        short8 bfr[5][4];
#pragma unroll
        for (int nt = 0; nt < 5; nt++)
#pragma unroll
            for (int kt = 0; kt < 4; kt++) {
                int row = w * 80 + nt * 16 + lm;
                const float* src = (row < 256)
                    ? gateW + (size_t)row * 384 + 256 + kt * 32 + lh * 8
                    : WsW + (size_t)(row - 256) * 128 + kt * 32 + lh * 8;
                float4 f0 = *(const float4*)src;
                float4 f1 = *(const float4*)(src + 4);
                union { unsigned u[4]; short8 s; } tmp;
                tmp.u[0] = cvt_pk(f0.x, f0.y); tmp.u[1] = cvt_pk(f0.z, f0.w);
                tmp.u[2] = cvt_pk(f1.x, f1.y); tmp.u[3] = cvt_pk(f1.z, f1.w);
                bfr[nt][kt] = tmp.s;
            }
        __syncthreads();

        short8 afr[2][4];
#pragma unroll
        for (int mt = 0; mt < 2; mt++)
#pragma unroll
            for (int kt = 0; kt < 4; kt++) {
                int row = mt * 16 + lm;
                afr[mt][kt] = *(const short8*)(a_lds +
                    ((row * 256 + kt * 64 + lh * 16) ^ ((row & 7) << 4)));
            }
        f32x4 acc[2][5];
#pragma unroll
        for (int mt = 0; mt < 2; mt++)
#pragma unroll
            for (int nt = 0; nt < 5; nt++) acc[mt][nt] = (f32x4){0.f, 0.f, 0.f, 0.f};
#pragma unroll
        for (int kt = 0; kt < 4; kt++)
#pragma unroll
            for (int mt = 0; mt < 2; mt++)
#pragma unroll
                for (int nt = 0; nt < 5; nt++)
                    acc[mt][nt] = __builtin_amdgcn_mfma_f32_16x16x32_bf16(
                        afr[mt][kt], bfr[nt][kt], acc[mt][nt], 0, 0, 0);

#pragma unroll
        for (int mt = 0; mt < 2; mt++)
#pragma unroll
            for (int nt = 0; nt < 5; nt++) {
                int wrow = w * 80 + nt * 16 + lm;
#pragma unroll
                for (int r = 0; r < 4; r++) {
                    int node = nbase + mt * 16 + lh * 4 + r;
                    if (node < nNode) {
                        ushort_t v = f2bf(acc[mt][nt][r]);
                        if (wrow < 256)
                            gate_hs[(size_t)node * 256 + 2 * (wrow & 127) + (wrow >> 7)] = v;
                        else
                            ws_hs[(size_t)node * 64 + wrow - 256] = v;
                    }
                }
            }
    } else if (bid < nodeB + tableB) {
        // ---------------- table path ----------------
        float* x = (float*)smem;
        int b = bid - nodeB;
        bool isRel = b < vocab;
        int src = isRel ? b : q_rel[b - vocab];
        if (t < 128) x[t] = rela[src * 128 + t];
        __syncthreads();
        const float4* x4 = (const float4*)x;
        {
            const float4* wrow = (const float4*)(gateW + t * 384 + (isRel ? 0 : 128));
            float acc = isRel ? 0.0f : gateW_b[t];
#pragma unroll 8
            for (int i = 0; i < 32; i++) acc += dot4(wrow[i], x4[i]);
            float* dst = isRel ? (grhr + b * 256) : (gq + (b - vocab) * 256);
            dst[2 * (t & 127) + (t >> 7)] = acc;
        }
        if (isRel) {
            if (t < 192) {
                bool isWr = t < 64;
                int i = isWr ? t : (t - 64);
                const float* wp = isWr ? (WrW + i * 128) : (htW + i * 256);
                const float4* wrow = (const float4*)wp;
                float acc = isWr ? 0.0f : ht_b[i];
#pragma unroll 8
                for (int q = 0; q < 32; q++) acc += dot4(wrow[q], x4[q]);
                if (isWr) whr[b * 64 + i] = acc;
                else      thr[b * 128 + i] = acc;
            }
        } else {
            if (t < 64) {
                const float4* wrow = (const float4*)(WqrW + t * 128);
                float acc = Wqr_b[t];
#pragma unroll 8
                for (int q = 0; q < 32; q++) acc += dot4(wrow[q], x4[q]);
                wq[(b - vocab) * 64 + t] = acc;
            }
        }
    } else {
        // ---------------- hist path ----------------
        int i = (bid - nodeB - tableB) * 256 + t;
        if (i < nEdge) atomicAdd(cnt + edges[(size_t)i * 7 + 5], 1);
    }
}

// ---------------------------------------------------------------------------
// Scan (two-level) over obj counts.
// ---------------------------------------------------------------------------
__global__ __launch_bounds__(256) void scan1_kernel(
    const int* __restrict__ cnt, int n, int* __restrict__ partials)
{
    __shared__ int s[256];
    int t = threadIdx.x;
    int i = blockIdx.x * 256 + t;
    s[t] = (i < n) ? cnt[i] : 0;
    __syncthreads();
    for (int o = 128; o > 0; o >>= 1) {
        if (t < o) s[t] += s[t + o];
        __syncthreads();
    }
    if (t == 0) partials[blockIdx.x] = s[0];
}

__global__ __launch_bounds__(256) void scan2_kernel(
    const int* __restrict__ cnt, int n, const int* __restrict__ partials,
    int nBlk, int* __restrict__ cursor)
{
    __shared__ int ps[256];
    __shared__ int loc[256];
    int t = threadIdx.x, b = blockIdx.x;
    ps[t] = (t < nBlk) ? partials[t] : 0;
    __syncthreads();
    for (int o = 1; o < 256; o <<= 1) {
        int v = (t >= o) ? ps[t - o] : 0;
        __syncthreads();
        ps[t] += v;
        __syncthreads();
    }
    int offset = (b > 0) ? ps[b - 1] : 0;
    int i = b * 256 + t;
    int v = (i < n) ? cnt[i] : 0;
    loc[t] = v;
    __syncthreads();
    for (int o = 1; o < 256; o <<= 1) {
        int x = (t >= o) ? loc[t - o] : 0;
        __syncthreads();
        loc[t] += x;
        __syncthreads();
    }
    if (i < n) cursor[i] = offset + loc[t] - v;
}

__global__ __launch_bounds__(256) void build_kernel(
    const int* __restrict__ edges, int nEdge, int* __restrict__ cursor,
    int4* __restrict__ sorted)
{
    int i = blockIdx.x * 256 + threadIdx.x;
    if (i < nEdge) {
        const int* er = edges + (size_t)i * 7;
        int obj = er[5];
        int s = atomicAdd(cursor + obj, 1);
        sorted[s] = make_int4(er[0], er[2], er[4], obj);
    }
}

// ---------------------------------------------------------------------------
// Edge kernel: 32 obj-sorted edges/block, 4 waves; wave w owns dims [32w,32w+32).
// Loop A: independent per-edge gather+gates+x/AB-stores (pre-sga), aa partial.
// Then: thr -> acc init, batched 8-way butterflies, sga -> LDS.
// Phase 2: MFMA (C pre-loaded with thr). Epilogue: run-reduced atomics.
// ---------------------------------------------------------------------------
__global__ __launch_bounds__(256, 6) void edge_kernel(
    const int4* __restrict__ sorted, int nEdge,
    const float* __restrict__ grhr, const float* __restrict__ gq,
    const float* __restrict__ whr, const float* __restrict__ wq,
    const float* __restrict__ thr,
    const ushort_t* __restrict__ gate_hs, const ushort_t* __restrict__ ws_hs,
    const ushort_t* __restrict__ hsb,
    const float* __restrict__ walpha, const float* __restrict__ htW,
    float* __restrict__ agg)
{
    __shared__ ushort_t xb[32 * 128];   // 8 KB, x bf16, swz ^((e&7)<<4)
    __shared__ unsigned ab[32 * 128];   // 16 KB, (A',B') bf16 pair, swz ^(((e>>2)&3)<<6)
    __shared__ float sgaL[32];
    __shared__ int4 eds4[32];

    int t = threadIdx.x, w = t >> 6, l = t & 63;
    int lm = l & 15, lh = l >> 4;
    int n0 = w * 32;

    // bijective XCD swizzle: contiguous edge (= obj) ranges per XCD
    int nb = gridDim.x;
    int xcd = blockIdx.x & 7, lid = blockIdx.x >> 3;
    int q = nb >> 3, rr = nb & 7;
    int sbid = ((xcd < rr) ? xcd * (q + 1) : rr * (q + 1) + (xcd - rr) * q) + lid;
    int ebase = sbid * 32;

    if (t < 32) {
        int gi = ebase + t;
        eds4[t] = (gi < nEdge) ? sorted[gi] : make_int4(0, 0, 0, -1);
    }

    // B fragments (W2 = htW[:,128:256] bf16) in VGPRs
    short8 bfr[2][4];
#pragma unroll
    for (int nt = 0; nt < 2; nt++)
#pragma unroll
        for (int kt = 0; kt < 4; kt++) {
            const float* src = htW + (size_t)(n0 + nt * 16 + lm) * 256 + 128 + kt * 32 + lh * 8;
            float4 f0 = *(const float4*)src;
            float4 f1 = *(const float4*)(src + 4);
            union { unsigned u[4]; short8 s; } tmp;
            tmp.u[0] = cvt_pk(f0.x, f0.y); tmp.u[1] = cvt_pk(f0.z, f0.w);
            tmp.u[2] = cvt_pk(f1.x, f1.y); tmp.u[3] = cvt_pk(f1.z, f1.w);
            bfr[nt][kt] = tmp.s;
        }
    float wal = walpha[l];
    __syncthreads();   // eds4 ready

    // --- Loop A: independent per-edge work ---
    float aa8[8];
#pragma unroll
    for (int i = 0; i < 8; i++) {
        int e = w * 8 + i;
        int4 er = eds4[e];
        int ridx = er.x, rel = er.y, sub = er.z;
        ushort4 gp = *(const ushort4*)(gate_hs + (size_t)sub * 256 + 4 * l);
        float4 ga = *(const float4*)(grhr + (size_t)rel * 256 + 4 * l);
        float4 gb = *(const float4*)(gq + (size_t)ridx * 256 + 4 * l);
        unsigned hp = *(const unsigned*)(hsb + (size_t)sub * 128 + 2 * l);
        float aw = bf2f(ws_hs[(size_t)sub * 64 + l]) + whr[rel * 64 + l] + wq[ridx * 64 + l];
        float h0 = bf2f((ushort_t)(hp & 0xffffu));
        float h1 = bf2f((ushort_t)(hp >> 16));
        float u0 = sigm(ga.x + gb.x + bf2f(gp.x));
        float r0 = sigm(ga.y + gb.y + bf2f(gp.y));
        float u1 = sigm(ga.z + gb.z + bf2f(gp.z));
        float r1 = sigm(ga.w + gb.w + bf2f(gp.w));
        *(unsigned*)((char*)xb + ((e * 256 + 4 * l) ^ ((e & 7) << 4))) = cvt_pk(r0 * h0, r1 * h1);
        uint2 abp;
        abp.x = cvt_pk((1.0f - u0) * h0, u0);
        abp.y = cvt_pk((1.0f - u1) * h1, u1);
        *(uint2*)((char*)ab + ((e * 512 + 8 * l) ^ (((e >> 2) & 3) << 6))) = abp;
        aw = (aw > 0.0f) ? aw : 0.01f * aw;
        aa8[i] = aw * wal;
    }

    // --- acc init = thr[rel][d] (C of MFMA); latency hidden under butterflies ---
    f32x4 acc[2][2];
#pragma unroll
    for (int mt = 0; mt < 2; mt++)
#pragma unroll
        for (int nt = 0; nt < 2; nt++) {
            int d = n0 + nt * 16 + lm;
#pragma unroll
            for (int r = 0; r < 4; r++) {
                int rel = eds4[mt * 16 + lh * 4 + r].y;
                acc[mt][nt][r] = thr[rel * 128 + d];
            }
        }

    // --- batched butterflies (8-way ILP) ---
#pragma unroll
    for (int o = 32; o > 0; o >>= 1) {
#pragma unroll
        for (int i = 0; i < 8; i++) aa8[i] += __shfl_xor(aa8[i], o, 64);
    }
#pragma unroll
    for (int i = 0; i < 8; i++) {
        float s = sigm(aa8[i]);
        if (l == i) sgaL[w * 8 + i] = s;
    }
    __syncthreads();

    // --- Phase 2: MFMA C[32 edges][32 dims] (C pre-loaded with thr) ---
    short8 afr[2][4];
#pragma unroll
    for (int mt = 0; mt < 2; mt++)
#pragma unroll
        for (int kt = 0; kt < 4; kt++) {
            int e = mt * 16 + lm;
            afr[mt][kt] = *(const short8*)((const char*)xb +
                ((e * 256 + kt * 64 + lh * 16) ^ ((e & 7) << 4)));
        }
#pragma unroll
    for (int kt = 0; kt < 4; kt++)
#pragma unroll
        for (int mt = 0; mt < 2; mt++)
#pragma unroll
            for (int nt = 0; nt < 2; nt++)
                acc[mt][nt] = __builtin_amdgcn_mfma_f32_16x16x32_bf16(
                    afr[mt][kt], bfr[nt][kt], acc[mt][nt], 0, 0, 0);

    // --- Epilogue: run-reduced atomics along each lane's 4 consecutive edges ---
#pragma unroll
    for (int mt = 0; mt < 2; mt++)
#pragma unroll
        for (int nt = 0; nt < 2; nt++) {
            int d = n0 + nt * 16 + lm;
            float vals[4];
            int objs[4];
#pragma unroll
            for (int r = 0; r < 4; r++) {
                int e = mt * 16 + lh * 4 + r;
                objs[r] = eds4[e].w;
                float cand = tanh_fast(acc[mt][nt][r]);
                unsigned abw = *(const unsigned*)((const char*)ab +
                    ((e * 512 + 4 * d) ^ (((e >> 2) & 3) << 6)));
                vals[r] = sgaL[e] * (bf2f((ushort_t)(abw & 0xffffu)) +
                                     bf2f((ushort_t)(abw >> 16)) * cand);
            }
            float sum = vals[0];
            int prev = objs[0];
#pragma unroll
            for (int r = 1; r < 4; r++) {
                if (objs[r] == prev) {
                    sum += vals[r];
                } else {
                    if (prev >= 0) atomicAdd(agg + (size_t)prev * 128 + d, sum);
                    sum = vals[r];
                    prev = objs[r];
                }
            }
            if (prev >= 0) atomicAdd(agg + (size_t)prev * 128 + d, sum);
        }
}

// ---------------------------------------------------------------------------
// Final (MFMA): out[n] = (agg[n]/sqrt(deg[n]+1e-4)) @ Wh.T, in place.
// ---------------------------------------------------------------------------
__global__ __launch_bounds__(256) void final_kernel(
    const float* __restrict__ WhW, const int* __restrict__ degi,
    float* __restrict__ agg, int nNode)
{
    __shared__ char y_lds[64 * 256];
    int t = threadIdx.x, w = t >> 6, l = t & 63;
    int lm = l & 15, lh = l >> 4;
    int nbase = blockIdx.x * 64;

    short8 bfr[2][4];
#pragma unroll
    for (int nt = 0; nt < 2; nt++)
#pragma unroll
        for (int kt = 0; kt < 4; kt++) {
            const float* src = WhW + (size_t)(w * 32 + nt * 16 + lm) * 128 + kt * 32 + lh * 8;
            float4 f0 = *(const float4*)src;
            float4 f1 = *(const float4*)(src + 4);
            union { unsigned u[4]; short8 s; } tmp;
            tmp.u[0] = cvt_pk(f0.x, f0.y); tmp.u[1] = cvt_pk(f0.z, f0.w);
            tmp.u[2] = cvt_pk(f1.x, f1.y); tmp.u[3] = cvt_pk(f1.z, f1.w);
            bfr[nt][kt] = tmp.s;
        }

    for (int idx = t; idx < 2048; idx += 256) {
        int row = idx >> 5, c4 = idx & 31;
        int node = nbase + row;
        uint2 p = {0u, 0u};
        if (node < nNode) {
            float4 v = ((const float4*)agg)[(size_t)node * 32 + c4];
            float r = 1.0f / sqrtf((float)degi[node] + 1e-4f);
            p.x = cvt_pk(v.x * r, v.y * r);
            p.y = cvt_pk(v.z * r, v.w * r);
        }
        *(uint2*)(y_lds + ((row * 256 + c4 * 8) ^ ((row & 7) << 4))) = p;
    }
    __syncthreads();

    short8 afr[4][4];
#pragma unroll
    for (int mt = 0; mt < 4; mt++)
#pragma unroll
        for (int kt = 0; kt < 4; kt++) {
            int row = mt * 16 + lm;
            afr[mt][kt] = *(const short8*)(y_lds +
                ((row * 256 + kt * 64 + lh * 16) ^ ((row & 7) << 4)));
        }
    f32x4 acc[4][2];
#pragma unroll
    for (int mt = 0; mt < 4; mt++)
#pragma unroll
        for (int nt = 0; nt < 2; nt++) acc[mt][nt] = (f32x4){0.f, 0.f, 0.f, 0.f};
#pragma unroll
    for (int kt = 0; kt < 4; kt++)
#pragma unroll
        for (int mt = 0; mt < 4; mt++)
#pragma unroll
            for (int nt = 0; nt < 2; nt++)
                acc[mt][nt] = __builtin_amdgcn_mfma_f32_16x16x32_bf16(
                    afr[mt][kt], bfr[nt][kt], acc[mt][nt], 0, 0, 0);

#pragma unroll
    for (int mt = 0; mt < 4; mt++)
#pragma unroll
        for (int nt = 0; nt < 2; nt++) {
            int col = w * 32 + nt * 16 + lm;
#pragma unroll
            for (int r = 0; r < 4; r++) {
                int node = nbase + mt * 16 + lh * 4 + r;
                if (node < nNode) agg[(size_t)node * 128 + col] = acc[mt][nt][r];
            }
        }
}

extern "C" void kernel_launch(void* const* d_in, const int* in_sizes, int n_in,
                              void* d_out, int out_size, void* d_ws, size_t ws_size,
                              hipStream_t stream)
{
    const int*   q_rel   = (const int*)d_in[1];
    const float* hidden  = (const float*)d_in[2];
    const int*   edges   = (const int*)d_in[3];
    const float* rela    = (const float*)d_in[5];
    const float* WsW     = (const float*)d_in[6];
    const float* WrW     = (const float*)d_in[7];
    const float* WqrW    = (const float*)d_in[8];
    const float* Wqr_b   = (const float*)d_in[9];
    const float* walpha  = (const float*)d_in[10];
    const float* gateW   = (const float*)d_in[11];
    const float* gateW_b = (const float*)d_in[12];
    const float* htW     = (const float*)d_in[13];
    const float* ht_b    = (const float*)d_in[14];
    const float* WhW     = (const float*)d_in[15];

    int nNode  = in_sizes[2] / 128;
    int nEdge  = in_sizes[3] / 7;
    int vocab  = in_sizes[5] / 128;
    int nQuery = in_sizes[1];

    char* ws = (char*)d_ws;
    size_t off = 0;
    auto alloc = [&](size_t bytes) { size_t o = off; off += (bytes + 255) & ~(size_t)255; return o; };
    int*      cntO    = (int*)(ws + alloc((size_t)(nNode + 256) * 4));
    int*      cursorO = (int*)(ws + alloc((size_t)(nNode + 256) * 4));
    int*      partials= (int*)(ws + alloc(256 * 4));
    int4*     sorted  = (int4*)(ws + alloc((size_t)nEdge * 16));
    float*    grhr    = (float*)(ws + alloc((size_t)vocab * 256 * 4));
    float*    whr     = (float*)(ws + alloc((size_t)vocab * 64 * 4));
    float*    thr     = (float*)(ws + alloc((size_t)vocab * 128 * 4));
    float*    gq      = (float*)(ws + alloc((size_t)nQuery * 256 * 4));
    float*    wq      = (float*)(ws + alloc((size_t)nQuery * 64 * 4));
    ushort_t* gate_hs = (ushort_t*)(ws + alloc((size_t)nNode * 256 * 2));
    ushort_t* ws_hs   = (ushort_t*)(ws + alloc((size_t)nNode * 64 * 2));
    ushort_t* hsb     = (ushort_t*)(ws + alloc((size_t)nNode * 128 * 2));
    if (off > ws_size) return;

    float* agg = (float*)d_out;
    hipMemsetAsync(agg, 0, (size_t)nNode * 128 * 4, stream);
    hipMemsetAsync(cntO, 0, (size_t)(nNode + 256) * 4, stream);

    int nodeB  = (nNode + 31) / 32;
    int tableB = vocab + nQuery;
    int histB  = (nEdge + 255) / 256;
    prep_kernel<<<nodeB + tableB + histB, 256, 0, stream>>>(
        hidden, gateW, WsW, gate_hs, ws_hs, hsb, nNode,
        rela, q_rel, gateW_b, WrW, WqrW, Wqr_b, htW, ht_b,
        grhr, gq, whr, wq, thr, vocab,
        edges, nEdge, cntO, nodeB, tableB);

    int nScan = nNode + 1;
    int nBlk = (nScan + 255) / 256;
    scan1_kernel<<<nBlk, 256, 0, stream>>>(cntO, nScan, partials);
    scan2_kernel<<<nBlk, 256, 0, stream>>>(cntO, nScan, partials, nBlk, cursorO);
    build_kernel<<<(nEdge + 255) / 256, 256, 0, stream>>>(edges, nEdge, cursorO, sorted);

    int eblocks = (nEdge + 31) / 32;
    edge_kernel<<<eblocks, 256, 0, stream>>>(
        sorted, nEdge, grhr, gq, whr, wq, thr,
        gate_hs, ws_hs, hsb, walpha, htW, agg);

    int fblocks = (nNode + 63) / 64;
    final_kernel<<<fblocks, 256, 0, stream>>>(WhW, cntO, agg, nNode);
}